// Round 4
// baseline (374.304 us; speedup 1.0000x reference)
//
#include <hip/hip_runtime.h>
#include <hip/hip_bf16.h>
#include <cstdint>

typedef unsigned short u16;
typedef __attribute__((ext_vector_type(8))) short short8;
typedef __attribute__((ext_vector_type(8))) unsigned short ushort8;
typedef __attribute__((ext_vector_type(4))) float f32x4;

#define NB   32
#define CIN  256
#define HH   56
#define WWID 56
#define HP   58
#define WP   58
#define COUT 256
#define NSPAT (NB*HH*WWID)   // 100352 = 784*128

// round-to-nearest-even f32 -> bf16 bits
__device__ __forceinline__ u16 f2bf(float f) {
  uint32_t u = __float_as_uint(f);
  u += 0x7FFFu + ((u >> 16) & 1u);
  return (u16)(u >> 16);
}

// global -> LDS direct copy, 16B per lane. LDS dest must be wave-uniform.
__device__ __forceinline__ void gload16(const void* g, void* lds) {
  auto* gp = reinterpret_cast<const __attribute__((address_space(1))) uint32_t*>(
      reinterpret_cast<uintptr_t>(g));
  auto* lp = reinterpret_cast<__attribute__((address_space(3))) uint32_t*>(
      reinterpret_cast<uintptr_t>(lds));
  __builtin_amdgcn_global_load_lds(gp, lp, 16, 0, 0);
}

// ---------------------------------------------------------------------------
// prep_x: bin_active + bf16 cast + NCHW->padded-NHWC transpose.
// grid (32, 58), block 256. Halo rows/cols zeroed.
// Phase 1 (rewritten): each thread batches 8 channel rows -> 16 independent
// float4 loads in flight (latency hidden), packs transposed ushort8 -> 8
// vector 16B LDS stores (was 64 scalar u16). Swizzle chunk' = c8 ^ (f4&7),
// identical 3-bit mask on both sides (round-3 verified).
// Phase 2: conflict-free b128 reads + coalesced 16B global stores (verified).
// ---------------------------------------------------------------------------
__global__ __launch_bounds__(256) void prep_x_kernel(const float* __restrict__ x,
                                                     u16* __restrict__ xbp) {
  const int n = blockIdx.x, hp = blockIdx.y, t = threadIdx.x;
  u16* row = xbp + ((size_t)(n*HP + hp))*WP*CIN;
  if (hp == 0 || hp == HP-1) {           // top/bottom halo row: all zeros
    uint32_t* p = (uint32_t*)row;
    for (int i = t; i < WP*CIN/2; i += 256) p[i] = 0;
    return;
  }
  const int h = hp - 1;
  __shared__ u16 lds[HH*CIN];            // 28 KB
  if (t < 224) {
    const int f4 = t % 14, cg = t / 14;  // f4: w-quad, cg in [0,16)
    const int sw = f4 & 7;
    #pragma unroll
    for (int it = 0; it < 2; it++) {
      const int c8 = it*16 + cg;         // 16B chunk index in [0,32)
      const int c0 = c8 * 8;
      const float* xc = x + (((size_t)n*CIN + c0)*HH + h)*WWID + f4*4;
      float4 v[8];
      #pragma unroll
      for (int r = 0; r < 8; r++) v[r] = *(const float4*)(xc + (size_t)r*HH*WWID);
      u16 o[8][4];
      #pragma unroll
      for (int r = 0; r < 8; r++) {
        const float m01 = 0.5f*(fabsf(v[r].x)+fabsf(v[r].y));
        const float m23 = 0.5f*(fabsf(v[r].z)+fabsf(v[r].w));
        o[r][0] = f2bf(v[r].x == 0.f ? 0.f : copysignf(m01, v[r].x));
        o[r][1] = f2bf(v[r].y == 0.f ? 0.f : copysignf(m01, v[r].y));
        o[r][2] = f2bf(v[r].z == 0.f ? 0.f : copysignf(m23, v[r].z));
        o[r][3] = f2bf(v[r].w == 0.f ? 0.f : copysignf(m23, v[r].w));
      }
      const int cs = (c8 ^ sw) << 3;     // swizzled chunk elem offset
      #pragma unroll
      for (int j = 0; j < 4; j++) {
        ushort8 pk = { o[0][j], o[1][j], o[2][j], o[3][j],
                       o[4][j], o[5][j], o[6][j], o[7][j] };
        *(ushort8*)&lds[(f4*4 + j)*CIN + cs] = pk;
      }
    }
  }
  __syncthreads();
  // side halo columns
  if (t < 128) ((uint32_t*)row)[t] = 0;                            // wp = 0
  else ((uint32_t*)(row + (WP-1)*CIN))[t-128] = 0;                 // wp = 57
  // interior: 56 w * 32 chunks of 16B = 1792 chunks, 7 per thread
  #pragma unroll
  for (int it = 0; it < 7; it++) {
    const int q = it*256 + t;
    const int w = q >> 5, ck = q & 31;
    const short8 v = *(const short8*)&lds[w*CIN + ((ck ^ ((w >> 2) & 7)) << 3)];
    *(short8*)(row + (size_t)(w+1)*CIN + (ck << 3)) = v;
  }
}

// ---------------------------------------------------------------------------
// prep_w: weight [co][ci][kh][kw] fp32 -> wr [kh*3+kw][co][ci] bf16
// ---------------------------------------------------------------------------
__global__ __launch_bounds__(256) void prep_w_kernel(const float* __restrict__ wsrc,
                                                     u16* __restrict__ wr) {
  const int idx = blockIdx.x*256 + threadIdx.x;   // co*256 + ci
  const int co = idx >> 8, ci = idx & 255;
  const float* s = wsrc + (size_t)idx*9;
  #pragma unroll
  for (int p = 0; p < 9; p++)
    wr[((size_t)p*COUT + co)*CIN + ci] = f2bf(s[p]);
}

// ---------------------------------------------------------------------------
// conv: implicit GEMM, 128x128 tile, 4 waves, 16x16x32 bf16 MFMA, BK=64,
// 36 K-steps (9 pos x 4 ci-chunks).
// DEPTH-3 COUNTED-VMCNT PIPELINE (T4): 3 LDS buffer sets (96 KB, 1 block/CU),
// raw s_barrier + asm s_waitcnt vmcnt(8) -- never drain to 0 in steady state.
// Tile t+2 staged during compute of t; wait only for t+1 at step end. Each
// tile's loads get ~1.5 steps of MFMA+ds_read time to land (covers L2 ~300cy).
// Loop-body vmem ops are EXCLUSIVELY the 8 gload_lds per step -> vmcnt
// arithmetic is exact. XCD swizzle (T1) + XOR LDS swizzle (T2) as verified.
// ---------------------------------------------------------------------------
__global__ __launch_bounds__(256) void conv_kernel(const u16* __restrict__ xbp,
                                                   const u16* __restrict__ wr,
                                                   const float* __restrict__ bias,
                                                   float* __restrict__ out) {
  __shared__ u16 ldsA[3][128*64];   // weights tiles (swizzled)  48 KB
  __shared__ u16 ldsB[3][128*64];   // xb tiles (swizzled)       48 KB
  const int t = threadIdx.x;
  const int wv = t >> 6, l = t & 63;
  const int bid = blockIdx.x;
  const int b9 = (bid & 7)*196 + (bid >> 3);     // XCD-contiguous remap (1568%8==0)
  const int ntile = b9 & 1, mtile = b9 >> 1;

  // staging: thread stages chunk c=l&7 of row r=(i*4+wv)*8+(l>>3);
  // source chunk is (l&7)^(l>>3) (row&7 == l>>3 since row base is 8-aligned)
  const int cs8 = (((l & 7) ^ (l >> 3)) << 3);
  const int rb  = wv*8 + (l >> 3);

  int base0[4];
  #pragma unroll
  for (int i = 0; i < 4; i++) {
    const int m  = mtile*128 + i*32 + rb;
    const int n  = m / 3136, hw = m % 3136;
    base0[i] = ((n*HP + hw/WWID)*WP + (hw%WWID))*CIN;  // padded-NHWC elem index
  }

  auto STAGE = [&](int buf, int ks) {
    const int pos = ks >> 2, cb = ks & 3;
    const int posoff = ((pos/3)*WP + (pos%3))*CIN;
    const int koff = cb*64 + cs8;
    #pragma unroll
    for (int i = 0; i < 4; i++) {
      const u16* gA = wr + (((pos*COUT + ntile*128 + i*32 + rb) << 8) + koff);
      gload16(gA, &ldsA[buf][(i*4 + wv)*512]);
      const u16* gB = xbp + base0[i] + posoff + koff;
      gload16(gB, &ldsB[buf][(i*4 + wv)*512]);
    }
  };

  f32x4 acc[4][4];
  #pragma unroll
  for (int a = 0; a < 4; a++)
    #pragma unroll
    for (int b = 0; b < 4; b++) {
      acc[a][b][0] = 0.f; acc[a][b][1] = 0.f; acc[a][b][2] = 0.f; acc[a][b][3] = 0.f;
    }

  // prologue: tiles 0 and 1 in flight; wait tile-0 (8 newest may remain)
  STAGE(0, 0);
  STAGE(1, 1);
  asm volatile("s_waitcnt vmcnt(8)" ::: "memory");
  __builtin_amdgcn_sched_barrier(0);
  __builtin_amdgcn_s_barrier();
  __builtin_amdgcn_sched_barrier(0);

  int cur = 0, nxt = 2;
  #pragma unroll 1
  for (int ks = 0; ks < 36; ks++) {
    if (ks < 34) STAGE(nxt, ks + 2);
    #pragma unroll
    for (int kk = 0; kk < 2; kk++) {
      const int ch = (l >> 4) + 4*kk;     // logical 16B chunk (k index / 8)
      short8 af[4], bfr[4];
      #pragma unroll
      for (int mi = 0; mi < 4; mi++) {
        const int r = (wv & 1)*64 + mi*16 + (l & 15);
        af[mi] = *(const short8*)&ldsA[cur][r*64 + ((ch ^ (r & 7)) << 3)];
      }
      #pragma unroll
      for (int ni = 0; ni < 4; ni++) {
        const int r = (wv >> 1)*64 + ni*16 + (l & 15);
        bfr[ni] = *(const short8*)&ldsB[cur][r*64 + ((ch ^ (r & 7)) << 3)];
      }
      #pragma unroll
      for (int mi = 0; mi < 4; mi++)
        #pragma unroll
        for (int ni = 0; ni < 4; ni++)
          acc[mi][ni] = __builtin_amdgcn_mfma_f32_16x16x32_bf16(af[mi], bfr[ni], acc[mi][ni], 0, 0, 0);
    }
    if (ks < 35) {
      if (ks < 34) { asm volatile("s_waitcnt vmcnt(8)" ::: "memory"); }  // t+1 landed; t+2 stays in flight
      else         { asm volatile("s_waitcnt vmcnt(0)" ::: "memory"); }  // drain last tile
      __builtin_amdgcn_sched_barrier(0);
      __builtin_amdgcn_s_barrier();
      __builtin_amdgcn_sched_barrier(0);
    }
    cur = (cur == 2) ? 0 : cur + 1;
    nxt = (nxt == 2) ? 0 : nxt + 1;
  }

  // epilogue: D col (lane&15) = spatial (contiguous w), D row = co
  const int co0 = ntile*128 + (wv & 1)*64 + ((l >> 4) << 2);
  float bi[4][4];
  #pragma unroll
  for (int mi = 0; mi < 4; mi++)
    #pragma unroll
    for (int j = 0; j < 4; j++)
      bi[mi][j] = bias[co0 + mi*16 + j];
  const int mb = mtile*128 + (wv >> 1)*64 + (l & 15);
  #pragma unroll
  for (int ni = 0; ni < 4; ni++) {
    const int m = mb + ni*16;
    const int n = m / 3136, hw = m % 3136;
    float* orow = out + (size_t)n*COUT*3136 + hw;
    #pragma unroll
    for (int mi = 0; mi < 4; mi++) {
      #pragma unroll
      for (int j = 0; j < 4; j++)
        orow[(size_t)(co0 + mi*16 + j)*3136] = acc[mi][ni][j] + bi[mi][j];
    }
  }
}

extern "C" void kernel_launch(void* const* d_in, const int* in_sizes, int n_in,
                              void* d_out, int out_size, void* d_ws, size_t ws_size,
                              hipStream_t stream) {
  const float* x      = (const float*)d_in[0];
  const float* weight = (const float*)d_in[1];
  const float* bias   = (const float*)d_in[2];
  float* out = (float*)d_out;

  u16* xbp = (u16*)d_ws;                                  // 32*58*58*256 bf16 = 55.1 MB
  u16* wrr = xbp + (size_t)NB*HP*WP*CIN;                  // 9*256*256 bf16 = 1.18 MB

  prep_x_kernel<<<dim3(NB, HP), 256, 0, stream>>>(x, xbp);
  prep_w_kernel<<<dim3(256), 256, 0, stream>>>(weight, wrr);
  conv_kernel<<<dim3(NSPAT/128 * 2), 256, 0, stream>>>(xbp, wrr, bias, out);
}

// Round 5
// 313.147 us; speedup vs baseline: 1.1953x; 1.1953x over previous
//
#include <hip/hip_runtime.h>
#include <hip/hip_bf16.h>
#include <cstdint>

typedef unsigned short u16;
typedef __attribute__((ext_vector_type(8))) short short8;
typedef __attribute__((ext_vector_type(8))) unsigned short ushort8;
typedef __attribute__((ext_vector_type(4))) float f32x4;

#define NB   32
#define CIN  256
#define HH   56
#define WWID 56
#define HP   58
#define WP   58
#define COUT 256
#define NSPAT (NB*HH*WWID)   // 100352 = 784*128

// round-to-nearest-even f32 -> bf16 bits
__device__ __forceinline__ u16 f2bf(float f) {
  uint32_t u = __float_as_uint(f);
  u += 0x7FFFu + ((u >> 16) & 1u);
  return (u16)(u >> 16);
}

// global -> LDS direct copy, 16B per lane. LDS dest must be wave-uniform.
__device__ __forceinline__ void gload16(const void* g, void* lds) {
  auto* gp = reinterpret_cast<const __attribute__((address_space(1))) uint32_t*>(
      reinterpret_cast<uintptr_t>(g));
  auto* lp = reinterpret_cast<__attribute__((address_space(3))) uint32_t*>(
      reinterpret_cast<uintptr_t>(lds));
  __builtin_amdgcn_global_load_lds(gp, lp, 16, 0, 0);
}

// ---------------------------------------------------------------------------
// prep_x: bin_active + bf16 cast + NCHW->padded-NHWC transpose (round-4 form).
// ---------------------------------------------------------------------------
__global__ __launch_bounds__(256) void prep_x_kernel(const float* __restrict__ x,
                                                     u16* __restrict__ xbp) {
  const int n = blockIdx.x, hp = blockIdx.y, t = threadIdx.x;
  u16* row = xbp + ((size_t)(n*HP + hp))*WP*CIN;
  if (hp == 0 || hp == HP-1) {           // top/bottom halo row: all zeros
    uint32_t* p = (uint32_t*)row;
    for (int i = t; i < WP*CIN/2; i += 256) p[i] = 0;
    return;
  }
  const int h = hp - 1;
  __shared__ u16 lds[HH*CIN];            // 28 KB
  if (t < 224) {
    const int f4 = t % 14, cg = t / 14;  // f4: w-quad, cg in [0,16)
    const int sw = f4 & 7;
    #pragma unroll
    for (int it = 0; it < 2; it++) {
      const int c8 = it*16 + cg;         // 16B chunk index in [0,32)
      const int c0 = c8 * 8;
      const float* xc = x + (((size_t)n*CIN + c0)*HH + h)*WWID + f4*4;
      float4 v[8];
      #pragma unroll
      for (int r = 0; r < 8; r++) v[r] = *(const float4*)(xc + (size_t)r*HH*WWID);
      u16 o[8][4];
      #pragma unroll
      for (int r = 0; r < 8; r++) {
        const float m01 = 0.5f*(fabsf(v[r].x)+fabsf(v[r].y));
        const float m23 = 0.5f*(fabsf(v[r].z)+fabsf(v[r].w));
        o[r][0] = f2bf(v[r].x == 0.f ? 0.f : copysignf(m01, v[r].x));
        o[r][1] = f2bf(v[r].y == 0.f ? 0.f : copysignf(m01, v[r].y));
        o[r][2] = f2bf(v[r].z == 0.f ? 0.f : copysignf(m23, v[r].z));
        o[r][3] = f2bf(v[r].w == 0.f ? 0.f : copysignf(m23, v[r].w));
      }
      const int cs = (c8 ^ sw) << 3;     // swizzled chunk elem offset
      #pragma unroll
      for (int j = 0; j < 4; j++) {
        ushort8 pk = { o[0][j], o[1][j], o[2][j], o[3][j],
                       o[4][j], o[5][j], o[6][j], o[7][j] };
        *(ushort8*)&lds[(f4*4 + j)*CIN + cs] = pk;
      }
    }
  }
  __syncthreads();
  if (t < 128) ((uint32_t*)row)[t] = 0;                            // wp = 0
  else ((uint32_t*)(row + (WP-1)*CIN))[t-128] = 0;                 // wp = 57
  #pragma unroll
  for (int it = 0; it < 7; it++) {
    const int q = it*256 + t;
    const int w = q >> 5, ck = q & 31;
    const short8 v = *(const short8*)&lds[w*CIN + ((ck ^ ((w >> 2) & 7)) << 3)];
    *(short8*)(row + (size_t)(w+1)*CIN + (ck << 3)) = v;
  }
}

// ---------------------------------------------------------------------------
// prep_w: weight [co][ci][kh][kw] fp32 -> wr [kh*3+kw][co][ci] bf16
// ---------------------------------------------------------------------------
__global__ __launch_bounds__(256) void prep_w_kernel(const float* __restrict__ wsrc,
                                                     u16* __restrict__ wr) {
  const int idx = blockIdx.x*256 + threadIdx.x;   // co*256 + ci
  const int co = idx >> 8, ci = idx & 255;
  const float* s = wsrc + (size_t)idx*9;
  #pragma unroll
  for (int p = 0; p < 9; p++)
    wr[((size_t)p*COUT + co)*CIN + ci] = f2bf(s[p]);
}

// ---------------------------------------------------------------------------
// conv: implicit GEMM, 128x128 tile, 4 waves, 16x16x32 bf16 MFMA, BK=64,
// 36 K-steps. ROUND-3 SCHEDULE (2 buffers, 64 KB, ~2 blocks/CU, one
// __syncthreads per step with stage(t+1) issued at step start) —
// + ADDRESSING MICRO-OPT: all staging pointers are named loop-carried
// pointers advanced by compile-time constants once per kernel position
// (cb*64 folds into the load's immediate offset); all ds_read offsets are
// precomputed loop-invariant VGPRs; buffer index static via 4-step unroll.
// Targets round-3's VALUBusy=54% (address recompute was ~60 VALU/step).
// ---------------------------------------------------------------------------
__global__ __launch_bounds__(256) void conv_kernel(const u16* __restrict__ xbp,
                                                   const u16* __restrict__ wr,
                                                   const float* __restrict__ bias,
                                                   float* __restrict__ out) {
  __shared__ u16 ldsA[2][128*64];   // weights tiles (swizzled)  32 KB
  __shared__ u16 ldsB[2][128*64];   // xb tiles (swizzled)       32 KB
  const int t = threadIdx.x;
  const int wv = t >> 6, l = t & 63;
  const int bid = blockIdx.x;
  const int b9 = (bid & 7)*196 + (bid >> 3);     // XCD-contiguous remap (1568%8==0)
  const int ntile = b9 & 1, mtile = b9 >> 1;

  // staging: thread stages chunk c=l&7 of row r=(i*4+wv)*8+(l>>3);
  // source chunk is (l&7)^(l>>3) (row&7 == l>>3 since row base is 8-aligned)
  const int cs8 = (((l & 7) ^ (l >> 3)) << 3);
  const int rb  = wv*8 + (l >> 3);

  // loop-carried staging pointers (pos 0), advanced by constants per pos
  const u16* pA0; const u16* pA1; const u16* pA2; const u16* pA3;
  const u16* pB0; const u16* pB1; const u16* pB2; const u16* pB3;
  {
    const int m0 = mtile*128 + 0*32 + rb, m1 = mtile*128 + 1*32 + rb;
    const int m2 = mtile*128 + 2*32 + rb, m3 = mtile*128 + 3*32 + rb;
    pA0 = wr + ((ntile*128 + 0*32 + rb) << 8) + cs8;
    pA1 = wr + ((ntile*128 + 1*32 + rb) << 8) + cs8;
    pA2 = wr + ((ntile*128 + 2*32 + rb) << 8) + cs8;
    pA3 = wr + ((ntile*128 + 3*32 + rb) << 8) + cs8;
    pB0 = xbp + ((m0/3136*HP + (m0%3136)/WWID)*WP + (m0%3136)%WWID)*CIN + cs8;
    pB1 = xbp + ((m1/3136*HP + (m1%3136)/WWID)*WP + (m1%3136)%WWID)*CIN + cs8;
    pB2 = xbp + ((m2/3136*HP + (m2%3136)/WWID)*WP + (m2%3136)%WWID)*CIN + cs8;
    pB3 = xbp + ((m3/3136*HP + (m3%3136)/WWID)*WP + (m3%3136)%WWID)*CIN + cs8;
  }

  // loop-invariant ds_read element offsets (swizzled)
  int offA[2][4], offB[2][4];
  #pragma unroll
  for (int kk = 0; kk < 2; kk++) {
    const int ch = (l >> 4) + 4*kk;
    #pragma unroll
    for (int mi = 0; mi < 4; mi++) {
      const int r = (wv & 1)*64 + mi*16 + (l & 15);
      offA[kk][mi] = r*64 + ((ch ^ (l & 7)) << 3);
    }
    #pragma unroll
    for (int ni = 0; ni < 4; ni++) {
      const int r = (wv >> 1)*64 + ni*16 + (l & 15);
      offB[kk][ni] = r*64 + ((ch ^ (l & 7)) << 3);
    }
  }

  f32x4 acc[4][4];
  #pragma unroll
  for (int a = 0; a < 4; a++)
    #pragma unroll
    for (int b = 0; b < 4; b++) {
      acc[a][b][0] = 0.f; acc[a][b][1] = 0.f; acc[a][b][2] = 0.f; acc[a][b][3] = 0.f;
    }

#define STAGE_C(buf, cboff) do {                                  \
    gload16(pA0 + (cboff), &ldsA[buf][(0*4 + wv)*512]);           \
    gload16(pB0 + (cboff), &ldsB[buf][(0*4 + wv)*512]);           \
    gload16(pA1 + (cboff), &ldsA[buf][(1*4 + wv)*512]);           \
    gload16(pB1 + (cboff), &ldsB[buf][(1*4 + wv)*512]);           \
    gload16(pA2 + (cboff), &ldsA[buf][(2*4 + wv)*512]);           \
    gload16(pB2 + (cboff), &ldsB[buf][(2*4 + wv)*512]);           \
    gload16(pA3 + (cboff), &ldsA[buf][(3*4 + wv)*512]);           \
    gload16(pB3 + (cboff), &ldsB[buf][(3*4 + wv)*512]);           \
  } while (0)

#define COMPUTE(buf) do {                                                        \
    _Pragma("unroll")                                                            \
    for (int kk = 0; kk < 2; kk++) {                                             \
      short8 af[4], bfv[4];                                                      \
      _Pragma("unroll")                                                          \
      for (int mi = 0; mi < 4; mi++)                                             \
        af[mi] = *(const short8*)&ldsA[buf][offA[kk][mi]];                       \
      _Pragma("unroll")                                                          \
      for (int ni = 0; ni < 4; ni++)                                             \
        bfv[ni] = *(const short8*)&ldsB[buf][offB[kk][ni]];                      \
      _Pragma("unroll")                                                          \
      for (int mi = 0; mi < 4; mi++)                                             \
        _Pragma("unroll")                                                        \
        for (int ni = 0; ni < 4; ni++)                                           \
          acc[mi][ni] = __builtin_amdgcn_mfma_f32_16x16x32_bf16(af[mi], bfv[ni], acc[mi][ni], 0, 0, 0); \
    }                                                                            \
  } while (0)

  STAGE_C(0, 0);                 // (pos0, cb0) -> buf0
  __syncthreads();

  #pragma unroll 1
  for (int pos = 0; pos < 8; pos++) {
    STAGE_C(1, 64);  COMPUTE(0); __syncthreads();
    STAGE_C(0, 128); COMPUTE(1); __syncthreads();
    STAGE_C(1, 192); COMPUTE(0); __syncthreads();
    // advance to next kernel position (compile-time-selectable constants)
    const int dB = (pos == 2 || pos == 5) ? (WWID*CIN) : CIN;  // row-jump or +1 col
    pA0 += COUT*CIN; pA1 += COUT*CIN; pA2 += COUT*CIN; pA3 += COUT*CIN;
    pB0 += dB; pB1 += dB; pB2 += dB; pB3 += dB;
    STAGE_C(0, 0);   COMPUTE(1); __syncthreads();
  }
  // pos == 8 peeled (no further prefetch)
  STAGE_C(1, 64);  COMPUTE(0); __syncthreads();
  STAGE_C(0, 128); COMPUTE(1); __syncthreads();
  STAGE_C(1, 192); COMPUTE(0); __syncthreads();
  COMPUTE(1);

#undef STAGE_C
#undef COMPUTE

  // epilogue: D col (lane&15) = spatial (contiguous w), D row = co
  const int co0 = ntile*128 + (wv & 1)*64 + ((l >> 4) << 2);
  float bi[4][4];
  #pragma unroll
  for (int mi = 0; mi < 4; mi++)
    #pragma unroll
    for (int j = 0; j < 4; j++)
      bi[mi][j] = bias[co0 + mi*16 + j];
  const int mb = mtile*128 + (wv >> 1)*64 + (l & 15);
  #pragma unroll
  for (int ni = 0; ni < 4; ni++) {
    const int m = mb + ni*16;
    const int n = m / 3136, hw = m % 3136;
    float* orow = out + (size_t)n*COUT*3136 + hw;
    #pragma unroll
    for (int mi = 0; mi < 4; mi++) {
      #pragma unroll
      for (int j = 0; j < 4; j++)
        orow[(size_t)(co0 + mi*16 + j)*3136] = acc[mi][ni][j] + bi[mi][j];
    }
  }
}

extern "C" void kernel_launch(void* const* d_in, const int* in_sizes, int n_in,
                              void* d_out, int out_size, void* d_ws, size_t ws_size,
                              hipStream_t stream) {
  const float* x      = (const float*)d_in[0];
  const float* weight = (const float*)d_in[1];
  const float* bias   = (const float*)d_in[2];
  float* out = (float*)d_out;

  u16* xbp = (u16*)d_ws;                                  // 32*58*58*256 bf16 = 55.1 MB
  u16* wrr = xbp + (size_t)NB*HP*WP*CIN;                  // 9*256*256 bf16 = 1.18 MB

  prep_x_kernel<<<dim3(NB, HP), 256, 0, stream>>>(x, xbp);
  prep_w_kernel<<<dim3(256), 256, 0, stream>>>(weight, wrr);
  conv_kernel<<<dim3(NSPAT/128 * 2), 256, 0, stream>>>(xbp, wrr, bias, out);
}